// Round 2
// baseline (1543.700 us; speedup 1.0000x reference)
//
#include <hip/hip_runtime.h>

// QuantizedConv2d: N=32, C_in=128, H=W=56, C_out=256, 3x3, pad 1, stride 1.
// y = clip(round((conv(x - zp_in, w) + bias) * (s_in*s_w/s_out) + zp_out), -128, 127)
// Output: quantized int8 VALUES stored as int32 (harness reads integer outputs
// as np.int32 — confirmed by round-1 absmax == 2^31 from a -0.0f bit pattern).

#define NB 32
#define CI 128
#define HH 56
#define WW 56
#define CO 256

// Block: 256 threads. Computes a tile of 4 output rows x 56 cols x 8 output
// channels for one image n. x-tile staged in LDS (zero-point pre-subtracted,
// zero padding). Weights read through block-uniform addresses -> scalar loads.
__global__ __launch_bounds__(256, 4) void qconv_kernel(
    const int* __restrict__ x, const int* __restrict__ wgt,
    const int* __restrict__ bias,
    const float* __restrict__ s_in, const float* __restrict__ s_w,
    const float* __restrict__ s_out,
    const int* __restrict__ zp_in_p, const int* __restrict__ zp_out_p,
    int* __restrict__ out)
{
    const int tid = threadIdx.x;
    const int cog = blockIdx.x;      // 0..31  -> 8 output channels each
    const int ht  = blockIdx.y;      // 0..13  -> 4 output rows each
    const int n   = blockIdx.z;      // 0..31
    const int co0 = cog * 8;
    const int h0  = ht * 4;
    const int zp  = *zp_in_p;

    __shared__ int xs[8][6][58];     // 8 ci x (4+2) rows x (56+2) cols, 11.1 KB

    const bool active = tid < 224;   // 4*56 = 224 output positions
    const int r = (active ? tid : 0) / 56;
    const int w = (active ? tid : 0) % 56;

    int acc[8];
    #pragma unroll
    for (int i = 0; i < 8; i++) acc[i] = 0;

    for (int ci0 = 0; ci0 < CI; ci0 += 8) {
        // ---- stage x chunk into LDS: value = x - zp (0 outside image) ----
        for (int idx = tid; idx < 8 * 6 * 58; idx += 256) {
            int c   = idx / (6 * 58);
            int rem = idx - c * (6 * 58);
            int row = rem / 58;
            int col = rem - row * 58;
            int gh = h0 - 1 + row;
            int gw = col - 1;
            int v = 0;
            if (gh >= 0 && gh < HH && gw >= 0 && gw < WW)
                v = x[((n * CI + ci0 + c) * HH + gh) * WW + gw] - zp;
            xs[c][row][col] = v;
        }
        __syncthreads();

        // ---- accumulate 8 ci planes x 8 co x 3x3 ----
        #pragma unroll 2
        for (int c = 0; c < 8; c++) {
            int xr[9];
            #pragma unroll
            for (int dr = 0; dr < 3; dr++)
                #pragma unroll
                for (int dc = 0; dc < 3; dc++)
                    xr[dr * 3 + dc] = xs[c][r + dr][w + dc];
            const int ci = ci0 + c;
            #pragma unroll
            for (int co = 0; co < 8; co++) {
                const int* wp = &wgt[((co0 + co) * CI + ci) * 9]; // uniform -> s_load
                int a = acc[co];
                #pragma unroll
                for (int k = 0; k < 9; k++)
                    a += __mul24(xr[k], wp[k]);   // v_mad_i32_i24, operands < 2^23
                acc[co] = a;
            }
        }
        __syncthreads();
    }

    if (active) {
        const float rs = (*s_in) * (*s_w) / (*s_out);
        const float zo = (float)(*zp_out_p);
        #pragma unroll
        for (int co = 0; co < 8; co++) {
            float y = (float)(acc[co] + bias[co0 + co]) * rs + zo;
            y = rintf(y);                          // nearest-even == jnp.round
            y = fminf(fmaxf(y, -128.f), 127.f);
            out[((n * CO + co0 + co) * HH + h0 + r) * WW + w] = (int)y;
        }
    }
}

extern "C" void kernel_launch(void* const* d_in, const int* in_sizes, int n_in,
                              void* d_out, int out_size, void* d_ws, size_t ws_size,
                              hipStream_t stream) {
    const int*   x    = (const int*)d_in[0];
    const int*   wgt  = (const int*)d_in[1];
    const int*   bias = (const int*)d_in[2];
    const float* si   = (const float*)d_in[3];
    const float* sw   = (const float*)d_in[4];
    const float* so   = (const float*)d_in[5];
    const int*   zpi  = (const int*)d_in[6];
    const int*   zpo  = (const int*)d_in[7];
    int* out = (int*)d_out;

    dim3 grid(CO / 8, HH / 4, NB);   // 32 x 14 x 32 = 14336 blocks
    qconv_kernel<<<grid, 256, 0, stream>>>(x, wgt, bias, si, sw, so, zpi, zpo, out);
}

// Round 3
// 270.390 us; speedup vs baseline: 5.7092x; 5.7092x over previous
//
#include <hip/hip_runtime.h>
#include <stdint.h>

// QuantizedConv2d int8 implicit GEMM via MFMA i32_16x16x64_i8.
// N=32, C_in=128, H=W=56, C_out=256, 3x3, pad 1, stride 1.
// y = clip(round((conv(x - zp_in, w) + bias) * (s_in*s_w/s_out) + zp_out), -128,127)
// conv(x - zp, w) = conv(x, w)[zero-padded] - zp * SC(co, border_class).
// Output int8 values stored as int32 (harness reads integer outputs as np.int32).

#define NB 32
#define CI 128
#define HH 56
#define WW 56
#define CO 256
#define SPA (HH * WW)            // 3136, divisible by 32 -> wave M-tiles never cross n
#define XP_BYTES (NB * SPA * CI) // 12845056
#define BP_BYTES (9 * 2 * 4 * CO * 16) // 294912

typedef int v4i __attribute__((ext_vector_type(4)));

// ---- pack x: int32 NCHW -> int8 NHWC (flat-M major, ci contiguous) ----
__global__ __launch_bounds__(256) void pack_x_kernel(const int* __restrict__ x,
                                                     int8_t* __restrict__ xp) {
    __shared__ int8_t tile[WW * CI];         // [w][ci], 7168 B
    const int h = blockIdx.x, n = blockIdx.y, tid = threadIdx.x;
    for (int idx = tid; idx < CI * WW; idx += 256) {
        int ci = idx / WW, w = idx - ci * WW;       // consecutive tid -> consecutive w
        int v = x[((n * CI + ci) * HH + h) * WW + w];
        tile[w * CI + ci] = (int8_t)v;
    }
    __syncthreads();
    const int* t32 = (const int*)tile;
    int* o32 = (int*)(xp + (size_t)(n * HH + h) * WW * CI);
    for (int j = tid; j < WW * CI / 4; j += 256) o32[j] = t32[j];
}

// ---- pack w: [co][ci][9] int32 -> Bp[tap][c64][quad][co][16 ci bytes] ----
__global__ __launch_bounds__(256) void pack_b_kernel(const int* __restrict__ wgt,
                                                     int8_t* __restrict__ bp) {
    int idx4 = blockIdx.x * 256 + threadIdx.x;       // < 73728
    int j4  = idx4 & 3;
    int co  = (idx4 >> 2) & 255;
    int q   = (idx4 >> 10) & 3;
    int c64 = (idx4 >> 12) & 1;
    int t   = idx4 >> 13;                            // 0..8
    int ci  = c64 * 64 + q * 16 + j4 * 4;
    unsigned p = 0;
    #pragma unroll
    for (int k = 0; k < 4; ++k) {
        int v = wgt[(co * CI + ci + k) * 9 + t];
        p |= (unsigned)(v & 0xff) << (8 * k);
    }
    ((int*)bp)[idx4] = (int)p;
}

// ---- SC[co][hc*3+wc]: sum of weights over taps valid for each border class ----
__global__ __launch_bounds__(64) void sc_kernel(const int* __restrict__ wgt,
                                                int* __restrict__ SC) {
    const int co = blockIdx.x, lane = threadIdx.x;
    int T[9];
    #pragma unroll
    for (int t = 0; t < 9; ++t)
        T[t] = wgt[(co * CI + lane) * 9 + t] + wgt[(co * CI + lane + 64) * 9 + t];
    for (int off = 32; off; off >>= 1)
        #pragma unroll
        for (int t = 0; t < 9; ++t) T[t] += __shfl_down(T[t], off);
    if (lane == 0) {
        for (int hc = 0; hc < 3; ++hc) {
            int dlo = (hc == 0) ? 1 : 0, dhi = (hc == 2) ? 1 : 2;
            for (int wc = 0; wc < 3; ++wc) {
                int clo = (wc == 0) ? 1 : 0, chi = (wc == 2) ? 1 : 2;
                int s = 0;
                for (int dr = dlo; dr <= dhi; ++dr)
                    for (int dc = clo; dc <= chi; ++dc) s += T[dr * 3 + dc];
                SC[co * 9 + hc * 3 + wc] = s;
            }
        }
    }
}

// ---- main: implicit GEMM, block = 128 M x 64 co, wave = 32 M x 64 co ----
__global__ __launch_bounds__(256, 2) void qconv_mfma(
    const int8_t* __restrict__ xp, const int8_t* __restrict__ bp,
    const int* __restrict__ SC, const int* __restrict__ bias,
    const float* __restrict__ si, const float* __restrict__ sw,
    const float* __restrict__ so,
    const int* __restrict__ zpi, const int* __restrict__ zpo,
    int* __restrict__ out)
{
    const int tid  = threadIdx.x, lane = tid & 63, wid = tid >> 6;
    const int quad = lane >> 4, lo16 = lane & 15;
    const int mbase  = blockIdx.x * 128 + wid * 32;
    const int cobase = blockIdx.y * 64;

    // per-lane A rows (two 16-row M tiles)
    const int r0 = mbase + lo16, r1 = r0 + 16;
    int n0 = r0 / SPA, rem0 = r0 - n0 * SPA, h0 = rem0 / WW, w0 = rem0 - h0 * WW;
    int n1 = r1 / SPA, rem1 = r1 - n1 * SPA, h1 = rem1 / WW, w1 = rem1 - h1 * WW;

    v4i acc[2][4];
    #pragma unroll
    for (int mt = 0; mt < 2; ++mt)
        #pragma unroll
        for (int ct = 0; ct < 4; ++ct) acc[mt][ct] = (v4i){0, 0, 0, 0};

    const v4i zero4 = (v4i){0, 0, 0, 0};
    const int aq = quad * 16;

    #pragma unroll 3
    for (int t = 0; t < 9; ++t) {
        const int dr = t / 3, dc = t - dr * 3;
        const int hh0 = h0 + dr - 1, ww0 = w0 + dc - 1;
        const int hh1 = h1 + dr - 1, ww1 = w1 + dc - 1;
        const bool v0 = ((unsigned)hh0 < HH) && ((unsigned)ww0 < WW);
        const bool v1 = ((unsigned)hh1 < HH) && ((unsigned)ww1 < WW);
        // NHWC flat addr: spatial index = r + (dr-1)*56 + (dc-1), times 128
        const int o0 = ((r0 + (dr - 1) * WW + (dc - 1)) << 7) + aq;
        const int o1 = ((r1 + (dr - 1) * WW + (dc - 1)) << 7) + aq;
        #pragma unroll
        for (int c = 0; c < 2; ++c) {
            v4i a0 = *(const v4i*)(xp + (v0 ? o0 + c * 64 : 0));
            v4i a1 = *(const v4i*)(xp + (v1 ? o1 + c * 64 : 0));
            if (!v0) a0 = zero4;
            if (!v1) a1 = zero4;
            const int bb = (((t * 2 + c) * 4 + quad) * 256 + cobase + lo16) * 16;
            #pragma unroll
            for (int ct = 0; ct < 4; ++ct) {
                v4i b = *(const v4i*)(bp + bb + ct * 256);
                acc[0][ct] = __builtin_amdgcn_mfma_i32_16x16x64_i8(a0, b, acc[0][ct], 0, 0, 0);
                acc[1][ct] = __builtin_amdgcn_mfma_i32_16x16x64_i8(a1, b, acc[1][ct], 0, 0, 0);
            }
        }
    }

    // ---- epilogue: requant + LDS transpose for coalesced stores ----
    const float rs = (*si) * (*sw) / (*so);
    const float zo = (float)(*zpo);
    const int   zp = *zpi;

    __shared__ int lt[4][64][33];            // [wave][co_local][m_local], padded

    #pragma unroll
    for (int mt = 0; mt < 2; ++mt) {
        #pragma unroll
        for (int i = 0; i < 4; ++i) {
            const int ml = mt * 16 + quad * 4 + i;       // C/D row = quad*4 + reg
            const int m  = mbase + ml;
            int nn = m / SPA, rm = m - nn * SPA;
            int hh = rm / WW, wp_ = rm - hh * WW;
            int hc = (hh == 0) ? 0 : ((hh == HH - 1) ? 2 : 1);
            int wc = (wp_ == 0) ? 0 : ((wp_ == WW - 1) ? 2 : 1);
            int cls = hc * 3 + wc;
            #pragma unroll
            for (int ct = 0; ct < 4; ++ct) {
                const int co = cobase + ct * 16 + lo16;  // C/D col = lane&15
                int a = acc[mt][ct][i] - zp * SC[co * 9 + cls] + bias[co];
                float y = rintf((float)a * rs + zo);
                y = fminf(fmaxf(y, -128.f), 127.f);
                lt[wid][ct * 16 + lo16][ml] = (int)y;
            }
        }
    }
    __syncthreads();

    const int nS   = mbase / SPA;            // uniform per wave (32 | 3136)
    const int remS = mbase - nS * SPA;
    const int m4   = (lane & 7) * 4;
    #pragma unroll
    for (int cc = 0; cc < 8; ++cc) {
        const int col = cc * 8 + (lane >> 3);           // co_local 0..63
        v4i v;
        v.x = lt[wid][col][m4 + 0];
        v.y = lt[wid][col][m4 + 1];
        v.z = lt[wid][col][m4 + 2];
        v.w = lt[wid][col][m4 + 3];
        const int oidx = (nS * CO + cobase + col) * SPA + remS + m4;  // 16B aligned
        *(v4i*)(out + oidx) = v;
    }
}

extern "C" void kernel_launch(void* const* d_in, const int* in_sizes, int n_in,
                              void* d_out, int out_size, void* d_ws, size_t ws_size,
                              hipStream_t stream) {
    const int*   x    = (const int*)d_in[0];
    const int*   wgt  = (const int*)d_in[1];
    const int*   bias = (const int*)d_in[2];
    const float* si   = (const float*)d_in[3];
    const float* sw   = (const float*)d_in[4];
    const float* so   = (const float*)d_in[5];
    const int*   zpi  = (const int*)d_in[6];
    const int*   zpo  = (const int*)d_in[7];
    int* out = (int*)d_out;

    int8_t* xp = (int8_t*)d_ws;
    int8_t* bp = xp + XP_BYTES;
    int*    sc = (int*)(bp + BP_BYTES);

    pack_x_kernel<<<dim3(HH, NB), 256, 0, stream>>>(x, xp);
    pack_b_kernel<<<BP_BYTES / 4 / 256, 256, 0, stream>>>(wgt, bp);
    sc_kernel<<<CO, 64, 0, stream>>>(wgt, sc);
    qconv_mfma<<<dim3(100352 / 128, CO / 64), 256, 0, stream>>>(
        xp, bp, sc, bias, si, sw, so, zpi, zpo, out);
}

// Round 4
// 235.642 us; speedup vs baseline: 6.5510x; 1.1475x over previous
//
#include <hip/hip_runtime.h>
#include <stdint.h>

// QuantizedConv2d int8 implicit GEMM via MFMA i32_16x16x64_i8.
// N=32, C_in=128, H=W=56, C_out=256, 3x3, pad 1, stride 1.
// y = clip(round((conv(x - zp_in, w) + bias) * (s_in*s_w/s_out) + zp_out), -128,127)
// Output int8 values stored as int32 (harness reads integer outputs as np.int32).
//
// Structure: B (all 9 taps x 128 ci x 64 co = 72 KB) staged into LDS ONCE via
// global_load_lds -> the K-loop is barrier-free. A fragments come from global
// (coalesced, L2-hot across the 9 taps) with one-tap-ahead register prefetch.
// Out-of-image taps read a 128-B zero page at xp+XP_BYTES (address select, no
// post-load fixup). Epilogue transposes through LDS (aliased onto dead B).

#define NB 32
#define CI 128
#define HH 56
#define WW 56
#define CO 256
#define SPA (HH * WW)            // 3136, divisible by 32 -> wave tiles never cross n
#define XP_BYTES (NB * SPA * CI) // 12845056 (16-aligned)
#define BP_BYTES (9 * 2 * 4 * 4 * 64 * 16) // 294912

typedef int v4i __attribute__((ext_vector_type(4)));

// ---- pack x: int32 NCHW -> int8 NHWC; also zero the 128-B zero page ----
__global__ __launch_bounds__(256) void pack_x_kernel(const int* __restrict__ x,
                                                     int8_t* __restrict__ xp) {
    __shared__ int8_t tile[WW][CI + 4];      // 132-B rows: transpose writes conflict-free
    const int h = blockIdx.x, n = blockIdx.y, tid = threadIdx.x;
    if (blockIdx.x == 0 && blockIdx.y == 0 && tid < 32)
        ((int*)(xp + XP_BYTES))[tid] = 0;    // zero page (d_ws is re-poisoned every call)
    for (int idx = tid; idx < CI * WW; idx += 256) {
        int ci = idx / WW, w = idx - ci * WW;        // consecutive tid -> consecutive w
        tile[w][ci] = (int8_t)x[((n * CI + ci) * HH + h) * WW + w];
    }
    __syncthreads();
    int* o32 = (int*)(xp + (size_t)(n * HH + h) * WW * CI);
    for (int j = tid; j < WW * CI / 4; j += 256) {
        int w = j >> 5, k = j & 31;                  // 32 dwords per 128-B ci row
        o32[j] = ((const int*)tile)[w * 33 + k];     // stride 33 -> conflict-free
    }
}

// ---- pack w -> Bp[t][c64][quad][coq][co64][16 ci bytes] ----
__global__ __launch_bounds__(256) void pack_b_kernel(const int* __restrict__ wgt,
                                                     int8_t* __restrict__ bp) {
    int idx4 = blockIdx.x * 256 + threadIdx.x;       // < 73728 output dwords
    int j4  = idx4 & 3;
    int col = (idx4 >> 2) & 63;
    int coq = (idx4 >> 8) & 3;
    int q   = (idx4 >> 10) & 3;
    int c64 = (idx4 >> 12) & 1;
    int t   = idx4 >> 13;                            // 0..8
    int ci  = c64 * 64 + q * 16 + j4 * 4;
    int co  = coq * 64 + col;
    unsigned p = 0;
    #pragma unroll
    for (int k = 0; k < 4; ++k) {
        int v = wgt[(co * CI + ci + k) * 9 + t];
        p |= (unsigned)(v & 0xff) << (8 * k);
    }
    ((int*)bp)[idx4] = (int)p;
}

// ---- SC[co][hc*3+wc]: weight sums over valid taps per border class ----
__global__ __launch_bounds__(64) void sc_kernel(const int* __restrict__ wgt,
                                                int* __restrict__ SC) {
    const int co = blockIdx.x, lane = threadIdx.x;
    int T[9];
    #pragma unroll
    for (int t = 0; t < 9; ++t)
        T[t] = wgt[(co * CI + lane) * 9 + t] + wgt[(co * CI + lane + 64) * 9 + t];
    for (int off = 32; off; off >>= 1)
        #pragma unroll
        for (int t = 0; t < 9; ++t) T[t] += __shfl_down(T[t], off);
    if (lane == 0) {
        for (int hc = 0; hc < 3; ++hc) {
            int dlo = (hc == 0) ? 1 : 0, dhi = (hc == 2) ? 1 : 2;
            for (int wc = 0; wc < 3; ++wc) {
                int clo = (wc == 0) ? 1 : 0, chi = (wc == 2) ? 1 : 2;
                int s = 0;
                for (int dr = dlo; dr <= dhi; ++dr)
                    for (int dc = clo; dc <= chi; ++dc) s += T[dr * 3 + dc];
                SC[co * 9 + hc * 3 + wc] = s;
            }
        }
    }
}

// ---- main: block = 128 M x 64 co, 4 waves of 32 M x 64 co; barrier-free K ----
__global__ __launch_bounds__(256, 2) void qconv_mfma(
    const int8_t* __restrict__ xp, const int8_t* __restrict__ bp,
    const int* __restrict__ SC, const int* __restrict__ bias,
    const float* __restrict__ si, const float* __restrict__ sw,
    const float* __restrict__ so,
    const int* __restrict__ zpi, const int* __restrict__ zpo,
    int* __restrict__ out)
{
    const int tid  = threadIdx.x, lane = tid & 63, wid = tid >> 6;
    const int quad = lane >> 4, lo16 = lane & 15;
    const int mbase  = blockIdx.x * 128 + wid * 32;
    const int coq    = blockIdx.y;
    const int cobase = coq * 64;

    __shared__ char smem[72 * 1024];         // B[72 units x 1KB]; epilogue aliases it

    // ---- stage B: 72 contiguous 1-KB wave-units via global_load_lds ----
    #pragma unroll
    for (int k = 0; k < 18; ++k) {
        const int u = wid + 4 * k;           // 0..71
        __builtin_amdgcn_global_load_lds(
            (const __attribute__((address_space(1))) void*)
                (bp + ((u * 4 + coq) << 10) + lane * 16),
            (__attribute__((address_space(3))) void*)(smem + (u << 10)),
            16, 0, 0);
    }

    // per-lane A rows (two 16-row M tiles)
    const int r0 = mbase + lo16, r1 = r0 + 16;
    const int n0 = r0 / SPA, rem0 = r0 - n0 * SPA, h0 = rem0 / WW, w0 = rem0 - h0 * WW;
    const int h1 = rem0 < SPA - 16 ? (rem0 + 16) / WW : (rem0 + 16 - SPA) / WW;
    const int w1 = (w0 + 16) % WW;           // r1 = r0+16: same n-crossing logic
    const int aq = quad * 16;

    v4i acc[2][4];
    #pragma unroll
    for (int mt = 0; mt < 2; ++mt)
        #pragma unroll
        for (int ct = 0; ct < 4; ++ct) acc[mt][ct] = (v4i){0, 0, 0, 0};

    v4i aC[2][2], aN[2][2];
    {   // tap 0 prefetch (dr=0, dc=0 -> offset -57 rows)
        const bool v0 = (h0 >= 1) && (w0 >= 1);
        const bool v1 = (h1 >= 1) && (w1 >= 1);
        const int off = (-WW - 1) * 128 + aq;
        const int o0 = v0 ? (r0 << 7) + off : XP_BYTES;
        const int o1 = v1 ? (r1 << 7) + off : XP_BYTES;
        aC[0][0] = *(const v4i*)(xp + o0);
        aC[0][1] = *(const v4i*)(xp + o0 + 64);
        aC[1][0] = *(const v4i*)(xp + o1);
        aC[1][1] = *(const v4i*)(xp + o1 + 64);
    }
    __syncthreads();                          // B staged (drains vmcnt)

    #pragma unroll
    for (int t = 0; t < 9; ++t) {
        if (t < 8) {                          // prefetch tap t+1
            const int tt = t + 1, dr = tt / 3, dc = tt - dr * 3;
            const bool v0 = ((unsigned)(h0 + dr - 1) < HH) && ((unsigned)(w0 + dc - 1) < WW);
            const bool v1 = ((unsigned)(h1 + dr - 1) < HH) && ((unsigned)(w1 + dc - 1) < WW);
            const int off = ((dr - 1) * WW + (dc - 1)) * 128 + aq;
            const int o0 = v0 ? (r0 << 7) + off : XP_BYTES;
            const int o1 = v1 ? (r1 << 7) + off : XP_BYTES;
            aN[0][0] = *(const v4i*)(xp + o0);
            aN[0][1] = *(const v4i*)(xp + o0 + 64);
            aN[1][0] = *(const v4i*)(xp + o1);
            aN[1][1] = *(const v4i*)(xp + o1 + 64);
        }
        #pragma unroll
        for (int c = 0; c < 2; ++c) {
            const int ub = ((t * 2 + c) * 4 + quad) * 1024 + lo16 * 16;
            #pragma unroll
            for (int ct = 0; ct < 4; ++ct) {
                v4i b = *(const v4i*)(smem + ub + ct * 256);
                acc[0][ct] = __builtin_amdgcn_mfma_i32_16x16x64_i8(aC[0][c], b, acc[0][ct], 0, 0, 0);
                acc[1][ct] = __builtin_amdgcn_mfma_i32_16x16x64_i8(aC[1][c], b, acc[1][ct], 0, 0, 0);
            }
        }
        #pragma unroll
        for (int mt = 0; mt < 2; ++mt)
            #pragma unroll
            for (int c = 0; c < 2; ++c) aC[mt][c] = aN[mt][c];
    }

    // ---- epilogue: requant + LDS transpose (aliased onto B) ----
    const float rs = (*si) * (*sw) / (*so);
    const float zo = (float)(*zpo);
    const int   zp = *zpi;

    __syncthreads();                          // all waves done reading B
    int* lt = (int*)smem + wid * (64 * 33);   // per-wave 8448-B region

    #pragma unroll
    for (int mt = 0; mt < 2; ++mt) {
        #pragma unroll
        for (int i = 0; i < 4; ++i) {
            const int ml = mt * 16 + quad * 4 + i;        // C/D row = quad*4 + reg
            const int m  = mbase + ml;
            const int nn = m / SPA, rm = m - nn * SPA;
            const int hh = rm / WW, wp_ = rm - hh * WW;
            const int hc = (hh == 0) ? 0 : ((hh == HH - 1) ? 2 : 1);
            const int wc = (wp_ == 0) ? 0 : ((wp_ == WW - 1) ? 2 : 1);
            const int cls = hc * 3 + wc;
            #pragma unroll
            for (int ct = 0; ct < 4; ++ct) {
                const int co = cobase + ct * 16 + lo16;   // C/D col = lane&15
                int a = acc[mt][ct][i] - zp * SC[co * 9 + cls] + bias[co];
                float y = rintf((float)a * rs + zo);
                y = fminf(fmaxf(y, -128.f), 127.f);
                lt[(ct * 16 + lo16) * 33 + ml] = (int)y;
            }
        }
    }
    // same-wave ds_write -> ds_read is in-order; no barrier needed

    const int nS   = mbase / SPA;             // wave-uniform (32 | 3136)
    const int remS = mbase - nS * SPA;
    const int m4   = (lane & 7) * 4;
    #pragma unroll
    for (int cc = 0; cc < 8; ++cc) {
        const int col = cc * 8 + (lane >> 3);             // co_local 0..63
        v4i v;
        v.x = lt[col * 33 + m4 + 0];
        v.y = lt[col * 33 + m4 + 1];
        v.z = lt[col * 33 + m4 + 2];
        v.w = lt[col * 33 + m4 + 3];
        const int oidx = (nS * CO + cobase + col) * SPA + remS + m4;  // 16-B aligned
        *(v4i*)(out + oidx) = v;
    }
}

extern "C" void kernel_launch(void* const* d_in, const int* in_sizes, int n_in,
                              void* d_out, int out_size, void* d_ws, size_t ws_size,
                              hipStream_t stream) {
    const int*   x    = (const int*)d_in[0];
    const int*   wgt  = (const int*)d_in[1];
    const int*   bias = (const int*)d_in[2];
    const float* si   = (const float*)d_in[3];
    const float* sw   = (const float*)d_in[4];
    const float* so   = (const float*)d_in[5];
    const int*   zpi  = (const int*)d_in[6];
    const int*   zpo  = (const int*)d_in[7];
    int* out = (int*)d_out;

    int8_t* xp = (int8_t*)d_ws;                 // XP_BYTES + 128-B zero page
    int8_t* bp = xp + XP_BYTES + 128;
    int*    sc = (int*)(bp + BP_BYTES);

    pack_x_kernel<<<dim3(HH, NB), 256, 0, stream>>>(x, xp);
    pack_b_kernel<<<BP_BYTES / 4 / 256, 256, 0, stream>>>(wgt, bp);
    sc_kernel<<<CO, 64, 0, stream>>>(wgt, sc);
    qconv_mfma<<<dim3(100352 / 128, CO / 64), 256, 0, stream>>>(
        xp, bp, sc, bias, si, sw, so, zpi, zpo, out);
}